// Round 1
// 196.651 us; speedup vs baseline: 1.1406x; 1.1406x over previous
//
#include <hip/hip_runtime.h>

#define BB   4
#define NGT  20
#define TT   8
#define PP   25600
#define CC   40
#define TPB  1024
#define SUPP 1e9f
#define INNER_TH 0.5f
#define FILLB 224   // fill blocks in kernel 1: 32 match + 224 fill = 256 = one per CU

// pack bits: [0]=claimed [1:6]=ml label [7:13]=mi id [14]=md valid
//            [15:20]=md class [21:25]=md raw-gt-index (for exact score recompute)
#define PK_CLAIM  1u
#define PK_LAB_SH 1
#define PK_ID_SH  7
#define PK_MDV    (1u << 14)
#define PK_MDC_SH 15
#define PK_MDN_SH 21

__device__ inline unsigned long long shfl_down_u64(unsigned long long v, int off) {
    unsigned lo = (unsigned)v, hi = (unsigned)(v >> 32);
    lo = __shfl_down(lo, off, 64);
    hi = __shfl_down(hi, off, 64);
    return ((unsigned long long)hi << 32) | (unsigned long long)lo;
}

// geometry for (b, raw n, t) — identical IEEE ops in match and scatter
__device__ inline float4 make_geo(const float* __restrict__ gt_boxes, int b, int n, int t) {
    const float* bx = gt_boxes + ((size_t)(b * NGT + n) * TT + t) * 4;
    float x1 = bx[0], y1 = bx[1], x2 = bx[2], y2 = bx[3];
    float4 g;
    g.x = __fmul_rn(__fadd_rn(x1, x2), 0.5f);
    g.y = __fmul_rn(__fadd_rn(y1, y2), 0.5f);
    g.z = fmaxf(__fsub_rn(x2, x1), 0.05f);
    g.w = fmaxf(__fsub_rn(y2, y1), 0.05f);
    return g;
}

// exact distance for grid point (px,py) vs gt geometry g — identical IEEE ops to ref
__device__ inline float point_dist(int px, int py, float4 g) {
    float rxv = __fdiv_rn((float)px + 0.5f, 160.0f);  // == ref_points formula exactly
    float ryv = __fdiv_rn((float)py + 0.5f, 160.0f);
    float dx = __fdiv_rn(__fsub_rn(g.x, rxv), g.z);
    float dy = __fdiv_rn(__fsub_rn(g.y, ryv), g.w);
    return __fadd_rn(__fmul_rn(dx, dx), __fmul_rn(dy, dy));  // no FMA contraction
}

// ---------------- kernel 1: blocks [0,32) = match (unchanged logic);
// ----------------           blocks [32,256) = concurrent zero-fill of md output ----
__global__ __launch_bounds__(TPB) void match_fill_kernel(
        const int*   __restrict__ gt_labels,
        const float* __restrict__ gt_boxes,
        const int*   __restrict__ gt_ids,
        unsigned* __restrict__ packs_g,   // [B*T][P]
        uint4*    __restrict__ md4) {     // md region of d_out, as uint4
    if (blockIdx.x >= BB * TT) {
        // md zero-fill: independent of match, overlaps match's latency-bound loop.
        const int MD4 = BB * TT * PP * CC / 4;      // 8,192,000 uint4
        const int stride = FILLB * TPB;             // 229,376
        uint4 z = make_uint4(0u, 0u, 0u, 0u);
        for (int i = (blockIdx.x - BB * TT) * TPB + (int)threadIdx.x; i < MD4; i += stride)
            md4[i] = z;
        return;
    }

    int bt = blockIdx.x;            // b*T + t
    int b  = bt >> 3;
    int t  = bt & 7;
    int tid = threadIdx.x;

    __shared__ unsigned s_pack[PP];           // 102400 B
    __shared__ float  s_area[NGT];
    __shared__ int    s_valid[NGT];
    __shared__ int    s_order[NGT];
    __shared__ int    s_any[NGT];             // one flag per active slot: never reused
    __shared__ float4 s_geo[NGT];
    __shared__ int4   s_meta[NGT];            // {label, id, active, raw n} (sorted order)
    __shared__ int    s_actlist[NGT];
    __shared__ int    s_actcnt;
    __shared__ unsigned long long s_wave[TPB / 64];
    __shared__ unsigned long long s_bcast;

    // ---- phase 0: zero pack state, per-gt mean area / validity ----
    {
        uint4 z = make_uint4(0u, 0u, 0u, 0u);
        for (int i = tid; i < PP / 4; i += TPB) ((uint4*)s_pack)[i] = z;
    }
    if (tid < NGT) {
        const float* bx = gt_boxes + (size_t)(b * NGT + tid) * TT * 4;
        float a[TT];
        int anyPos = 0;
        for (int f = 0; f < TT; f++) {
            float w = __fsub_rn(bx[f * 4 + 2], bx[f * 4 + 0]);
            float h = __fsub_rn(bx[f * 4 + 3], bx[f * 4 + 1]);
            a[f] = __fmul_rn(w, h);
            anyPos |= (w > 0.0f && h > 0.0f) ? 1 : 0;
        }
        // numpy pairwise sum order for n=8, then * 1/8
        float s = __fadd_rn(__fadd_rn(__fadd_rn(a[0], a[1]), __fadd_rn(a[2], a[3])),
                            __fadd_rn(__fadd_rn(a[4], a[5]), __fadd_rn(a[6], a[7])));
        s_area[tid]  = __fmul_rn(s, 0.125f);
        s_valid[tid] = (anyPos && gt_labels[b * NGT + tid] >= 0) ? 1 : 0;
        s_any[tid]   = 0;
    }
    __syncthreads();

    // ---- phase 1: stable ascending argsort by rank counting ----
    if (tid < NGT) {
        float an = s_area[tid];
        int r = 0;
        for (int m2 = 0; m2 < NGT; m2++) {
            float am = s_area[m2];
            r += (am < an || (am == an && m2 < tid)) ? 1 : 0;
        }
        s_order[r] = tid;
    }
    __syncthreads();

    // ---- phase 2: per sorted slot, this frame's geometry/meta; compact active list ----
    if (tid < NGT) {
        int n   = s_order[tid];
        int src = b * NGT + n;
        s_geo[tid] = make_geo(gt_boxes, b, n, t);
        int id = gt_ids[src * TT + t];
        int4 mm;
        mm.x = gt_labels[src];
        mm.y = id;
        mm.z = (s_valid[n] && id != -1) ? 1 : 0;
        mm.w = n;                              // raw index for scatter's score recompute
        s_meta[tid] = mm;
    }
    __syncthreads();
    if (tid == 0) {
        int c = 0;
        for (int k = 0; k < NGT; k++)
            if (s_meta[k].z) s_actlist[c++] = k;  // preserves sorted order
        s_actcnt = c;
    }
    __syncthreads();
    int actcnt = s_actcnt;

    for (int j = 0; j < actcnt; j++) {
        // invariant at loop top: all prior claims visible (barrier B / fallback barrier)
        int slot = s_actlist[j];
        int4 m  = s_meta[slot];
        float4 g = s_geo[slot];

        // conservative rect: superset of {d < 0.5} (|dx_n| < sqrt(0.5) per axis), +slop
        float ex = __fmul_rn(g.z, 0.70711f);
        float ey = __fmul_rn(g.w, 0.70711f);
        int x0 = max(0,   (int)floorf((g.x - ex) * 160.0f - 0.5f) - 1);
        int x1 = min(159, (int)ceilf ((g.x + ex) * 160.0f - 0.5f) + 1);
        int y0 = max(0,   (int)floorf((g.y - ey) * 160.0f - 0.5f) - 1);
        int y1 = min(159, (int)ceilf ((g.y + ey) * 160.0f - 0.5f) + 1);
        int rw = x1 - x0 + 1;
        int M  = rw * (y1 - y0 + 1);

        // single scan with inline claiming: if inner.any() the ref claims exactly the
        // unclaimed inner points — each point is visited by exactly one thread, so a
        // claim can't change any other decision for this gt. If no thread claims,
        // state is unchanged and the fallback below is exact.
        unsigned base = PK_CLAIM | ((unsigned)m.x << PK_LAB_SH) |
                        ((unsigned)m.y << PK_ID_SH) | PK_MDV |
                        ((unsigned)m.x << PK_MDC_SH) |
                        ((unsigned)m.w << PK_MDN_SH);
        int found = 0;
        {
            // division-free strided (r,c) walk: one div per gt, then stepping
            int r  = tid / rw;                 // only vector div in the loop body
            int c  = tid - r * rw;
            int dr = TPB / rw;                 // uniform per gt
            int dc = TPB - dr * rw;            // TPB % rw
            for (int i = tid; i < M; i += TPB) {
                int px = x0 + c;
                int py = y0 + r;
                int p  = py * 160 + px;
                if (!(s_pack[p] & PK_CLAIM)) {
                    float d = point_dist(px, py, g);
                    if (d < INNER_TH) {        // score recomputed in scatter from (n,p)
                        s_pack[p] = base;
                        found = 1;
                    }
                }
                c += dc; r += dr;
                if (c >= rw) { c -= rw; r++; }
            }
        }
        if (found) s_any[j] = 1;
        __syncthreads();                       // B: consensus + claims visible

        if (!s_any[j]) {
            // fallback: single argmin over suppressed full frame (exact ref semantics:
            // claimed points hold 1e9; ties -> first index). No claims happened above.
            unsigned long long key = ~0ULL;
            {
                int py = tid / 160;            // one div
                int px = tid - py * 160;
                for (int p = tid; p < PP; p += TPB) {
                    float deff;
                    if (s_pack[p] & PK_CLAIM) {
                        deff = SUPP;
                    } else {
                        deff = point_dist(px, py, g);
                    }
                    unsigned long long kk =
                        ((unsigned long long)__float_as_uint(deff) << 32) |
                        (unsigned long long)(unsigned)p;
                    key = (kk < key) ? kk : key;
                    px += 64; py += 6;         // 1024 = 6*160 + 64
                    if (px >= 160) { px -= 160; py++; }
                }
            }
            unsigned long long v = key;
            for (int off = 32; off > 0; off >>= 1) {
                unsigned long long o = shfl_down_u64(v, off);
                v = (o < v) ? o : v;
            }
            int lane = tid & 63, wave = tid >> 6;
            if (lane == 0) s_wave[wave] = v;
            __syncthreads();
            if (tid == 0) {
                unsigned long long mval = s_wave[0];
                for (int w = 1; w < TPB / 64; w++) mval = (s_wave[w] < mval) ? s_wave[w] : mval;
                s_bcast = mval;
            }
            __syncthreads();
            unsigned long long gmin = s_bcast;
            float minv = __uint_as_float((unsigned)(gmin >> 32));
            int minp = (int)(unsigned)(gmin & 0xffffffffu);
            if ((minp & (TPB - 1)) == tid) {   // unique owner thread
                unsigned npk = PK_CLAIM | ((unsigned)m.x << PK_LAB_SH) |
                               ((unsigned)m.y << PK_ID_SH);
                if (minv < SUPP) {
                    // winner was unclaimed: d >= 0.5 everywhere unclaimed => ref md
                    // write = 0 on an all-zero row: no md record.
                    s_pack[minp] = npk;
                } else {
                    // all points claimed (argmin of all-1e9 = index 0). ref writes
                    // md[minp][lab] = 0: erase prior record iff same class.
                    unsigned old = s_pack[minp];
                    unsigned mdbits = old & (PK_MDV | (63u << PK_MDC_SH) | (31u << PK_MDN_SH));
                    if ((old & PK_MDV) &&
                        ((old >> PK_MDC_SH) & 63u) == (unsigned)m.x) mdbits = 0u;
                    s_pack[minp] = npk | mdbits;
                }
            }
            __syncthreads();                   // fallback claim visible before next gt
        }
        // common path: barrier B already made this gt's claims visible
    }

    // ---- dump pack state (coalesced; consumed by scatter_kernel) ----
    __syncthreads();
    uint4* dst = (uint4*)(packs_g + (size_t)bt * PP);
    for (int i = tid; i < PP / 4; i += TPB) dst[i] = ((const uint4*)s_pack)[i];
}

// ---------------- kernel 2: dense ml/mi write + sparse md scatter ----------------
// md zeros were already written by kernel 1's fill blocks; only points carrying an
// md record (PK_MDV) get their single nonzero class score written here. Score
// recompute uses the exact same IEEE ops as before (make_geo + point_dist).
__global__ __launch_bounds__(256) void scatter_kernel(
        const unsigned* __restrict__ packs,
        const float*    __restrict__ gt_boxes,
        float* __restrict__ out) {
    const int    ML = BB * TT * PP;                  // 819200 floats
    const size_t MD = (size_t)BB * TT * PP * CC;     // 32768000 floats
    int f = blockIdx.x * 256 + threadIdx.x;          // uint4 index, [0, 204800)
    uint4 pk4 = ((const uint4*)packs)[f];

    float4 vml, vmi;
    vml.x = (pk4.x & PK_CLAIM) ? (float)((pk4.x >> PK_LAB_SH) & 63u) : -1.0f;
    vml.y = (pk4.y & PK_CLAIM) ? (float)((pk4.y >> PK_LAB_SH) & 63u) : -1.0f;
    vml.z = (pk4.z & PK_CLAIM) ? (float)((pk4.z >> PK_LAB_SH) & 63u) : -1.0f;
    vml.w = (pk4.w & PK_CLAIM) ? (float)((pk4.w >> PK_LAB_SH) & 63u) : -1.0f;
    vmi.x = (pk4.x & PK_CLAIM) ? (float)((pk4.x >> PK_ID_SH) & 127u) : -1.0f;
    vmi.y = (pk4.y & PK_CLAIM) ? (float)((pk4.y >> PK_ID_SH) & 127u) : -1.0f;
    vmi.z = (pk4.z & PK_CLAIM) ? (float)((pk4.z >> PK_ID_SH) & 127u) : -1.0f;
    vmi.w = (pk4.w & PK_CLAIM) ? (float)((pk4.w >> PK_ID_SH) & 127u) : -1.0f;
    ((float4*)out)[f] = vml;                         // ml
    ((float4*)(out + ML + MD))[f] = vmi;             // mi

    int pt0 = f << 2;
#pragma unroll
    for (int k = 0; k < 4; k++) {
        unsigned pk = (k == 0) ? pk4.x : (k == 1) ? pk4.y : (k == 2) ? pk4.z : pk4.w;
        if (pk & PK_MDV) {
            int pt  = pt0 + k;
            int cls = (int)((pk >> PK_MDC_SH) & 63u);
            int n   = (int)((pk >> PK_MDN_SH) & 31u);
            int bt  = pt / PP;
            int p   = pt - bt * PP;
            int py  = p / 160;
            int px  = p - py * 160;
            float4 g = make_geo(gt_boxes, bt >> 3, n, bt & 7);
            float d  = point_dist(px, py, g);
            out[ML + (size_t)pt * CC + cls] = __fsub_rn(1.0f, __fmul_rn(2.0f, d));
        }
    }
}

extern "C" void kernel_launch(void* const* d_in, const int* in_sizes, int n_in,
                              void* d_out, int out_size, void* d_ws, size_t ws_size,
                              hipStream_t stream) {
    const int*   gt_labels = (const int*)d_in[0];
    const float* gt_boxes  = (const float*)d_in[1];
    const int*   gt_ids    = (const int*)d_in[2];
    // d_in[3] = ref_points (regular 160x160 grid — computed exactly in-kernel)
    // d_in[4] = spatial_shapes (unused; H=W=160 fixed)

    unsigned* packs = (unsigned*)d_ws;            // 3.2 MB
    float*    outf  = (float*)d_out;

    // kernel 1: match on 32 blocks + md zero-fill on 224 blocks (overlapped)
    match_fill_kernel<<<BB * TT + FILLB, TPB, 0, stream>>>(
        gt_labels, gt_boxes, gt_ids, packs,
        (uint4*)(outf + BB * TT * PP));           // md region base (16B-aligned)

    // kernel 2: ml/mi dense + md sparse scatter
    scatter_kernel<<<(BB * TT * PP / 4) / 256, 256, 0, stream>>>(packs, gt_boxes, outf);
}

// Round 2
// 168.762 us; speedup vs baseline: 1.3291x; 1.1653x over previous
//
#include <hip/hip_runtime.h>

#define BB   4
#define NGT  20
#define TT   8
#define PP   25600
#define CC   40
#define TPB  1024
#define SUPP 1e9f
#define INNER_TH 0.5f
#define FILLB 224   // fill blocks in kernel 1: 32 match + 224 fill = 256 = one per CU

// pack bits: [0]=claimed [1:6]=ml label [7:13]=mi id [14]=md valid
//            [15:20]=md class [21:25]=md raw-gt-index (for exact score recompute)
#define PK_CLAIM  1u
#define PK_LAB_SH 1
#define PK_ID_SH  7
#define PK_MDV    (1u << 14)
#define PK_MDC_SH 15
#define PK_MDN_SH 21

__device__ inline unsigned long long shfl_down_u64(unsigned long long v, int off) {
    unsigned lo = (unsigned)v, hi = (unsigned)(v >> 32);
    lo = __shfl_down(lo, off, 64);
    hi = __shfl_down(hi, off, 64);
    return ((unsigned long long)hi << 32) | (unsigned long long)lo;
}

// geometry for (b, raw n, t) — identical IEEE ops in match and scatter
__device__ inline float4 make_geo(const float* __restrict__ gt_boxes, int b, int n, int t) {
    const float* bx = gt_boxes + ((size_t)(b * NGT + n) * TT + t) * 4;
    float x1 = bx[0], y1 = bx[1], x2 = bx[2], y2 = bx[3];
    float4 g;
    g.x = __fmul_rn(__fadd_rn(x1, x2), 0.5f);
    g.y = __fmul_rn(__fadd_rn(y1, y2), 0.5f);
    g.z = fmaxf(__fsub_rn(x2, x1), 0.05f);
    g.w = fmaxf(__fsub_rn(y2, y1), 0.05f);
    return g;
}

// exact distance for grid point (px,py) vs gt geometry g — identical IEEE ops to ref.
// NOTE: d separates as dxx(px) + dyy(py); the match kernel precomputes both axis
// tables with these exact ops and combines with the same final __fadd_rn, so the
// table path is bit-identical to this function (used directly only in scatter).
__device__ inline float point_dist(int px, int py, float4 g) {
    float rxv = __fdiv_rn((float)px + 0.5f, 160.0f);  // == ref_points formula exactly
    float ryv = __fdiv_rn((float)py + 0.5f, 160.0f);
    float dx = __fdiv_rn(__fsub_rn(g.x, rxv), g.z);
    float dy = __fdiv_rn(__fsub_rn(g.y, ryv), g.w);
    return __fadd_rn(__fmul_rn(dx, dx), __fmul_rn(dy, dy));  // no FMA contraction
}

// ---------------- kernel 1: blocks [0,32) = match (separable-dist tables);
// ----------------           blocks [32,256) = concurrent zero-fill of md output ----
__global__ __launch_bounds__(TPB) void match_fill_kernel(
        const int*   __restrict__ gt_labels,
        const float* __restrict__ gt_boxes,
        const int*   __restrict__ gt_ids,
        unsigned* __restrict__ packs_g,   // [B*T][P]
        uint4*    __restrict__ md4) {     // md region of d_out, as uint4
    if (blockIdx.x >= BB * TT) {
        // md zero-fill: independent of match, overlaps match's latency-bound loop.
        const int MD4 = BB * TT * PP * CC / 4;      // 8,192,000 uint4
        const int stride = FILLB * TPB;             // 229,376
        uint4 z = make_uint4(0u, 0u, 0u, 0u);
        for (int i = (blockIdx.x - BB * TT) * TPB + (int)threadIdx.x; i < MD4; i += stride)
            md4[i] = z;
        return;
    }

    int bt = blockIdx.x;            // b*T + t
    int b  = bt >> 3;
    int t  = bt & 7;
    int tid = threadIdx.x;

    __shared__ unsigned s_pack[PP];           // 102400 B
    __shared__ float  s_dxx[NGT * 160];       // 12800 B: per-slot column dx^2
    __shared__ float  s_dyy[NGT * 160];       // 12800 B: per-slot row dy^2
    __shared__ float  s_area[NGT];
    __shared__ int    s_valid[NGT];
    __shared__ int    s_order[NGT];
    __shared__ int    s_any[NGT];             // one flag per active slot: never reused
    __shared__ float4 s_geo[NGT];
    __shared__ int4   s_meta[NGT];            // {label, id, active, raw n} (sorted order)
    __shared__ int    s_actlist[NGT];
    __shared__ int    s_actcnt;
    __shared__ unsigned long long s_wave[TPB / 64];
    __shared__ unsigned long long s_bcast;

    // ---- phase 0: zero pack state, per-gt mean area / validity ----
    {
        uint4 z = make_uint4(0u, 0u, 0u, 0u);
        for (int i = tid; i < PP / 4; i += TPB) ((uint4*)s_pack)[i] = z;
    }
    if (tid < NGT) {
        const float* bx = gt_boxes + (size_t)(b * NGT + tid) * TT * 4;
        float a[TT];
        int anyPos = 0;
        for (int f = 0; f < TT; f++) {
            float w = __fsub_rn(bx[f * 4 + 2], bx[f * 4 + 0]);
            float h = __fsub_rn(bx[f * 4 + 3], bx[f * 4 + 1]);
            a[f] = __fmul_rn(w, h);
            anyPos |= (w > 0.0f && h > 0.0f) ? 1 : 0;
        }
        // numpy pairwise sum order for n=8, then * 1/8
        float s = __fadd_rn(__fadd_rn(__fadd_rn(a[0], a[1]), __fadd_rn(a[2], a[3])),
                            __fadd_rn(__fadd_rn(a[4], a[5]), __fadd_rn(a[6], a[7])));
        s_area[tid]  = __fmul_rn(s, 0.125f);
        s_valid[tid] = (anyPos && gt_labels[b * NGT + tid] >= 0) ? 1 : 0;
        s_any[tid]   = 0;
    }
    __syncthreads();

    // ---- phase 1: stable ascending argsort by rank counting ----
    if (tid < NGT) {
        float an = s_area[tid];
        int r = 0;
        for (int m2 = 0; m2 < NGT; m2++) {
            float am = s_area[m2];
            r += (am < an || (am == an && m2 < tid)) ? 1 : 0;
        }
        s_order[r] = tid;
    }
    __syncthreads();

    // ---- phase 2: per sorted slot, this frame's geometry/meta; compact active list ----
    if (tid < NGT) {
        int n   = s_order[tid];
        int src = b * NGT + n;
        s_geo[tid] = make_geo(gt_boxes, b, n, t);
        int id = gt_ids[src * TT + t];
        int4 mm;
        mm.x = gt_labels[src];
        mm.y = id;
        mm.z = (s_valid[n] && id != -1) ? 1 : 0;
        mm.w = n;                              // raw index for scatter's score recompute
        s_meta[tid] = mm;
    }
    __syncthreads();
    if (tid == 0) {
        int c = 0;
        for (int k = 0; k < NGT; k++)
            if (s_meta[k].z) s_actlist[c++] = k;  // preserves sorted order
        s_actcnt = c;
    }

    // ---- phase 2.5: separable distance tables, all slots at once ----
    // dxx[slot][px] = sq((cx - rx(px))/w), dyy[slot][py] = sq((cy - ry(py))/h),
    // built with the exact IEEE ops of point_dist. 6400 divisions total, fully
    // parallel, replaces 2 divisions per scanned point in the gt loop below.
    for (int i = tid; i < NGT * 320; i += TPB) {
        int slot = i / 320;                   // magic-mul, constant divisor
        int w    = i - slot * 320;
        float4 g = s_geo[slot];               // written before the last barrier
        if (w < 160) {
            float rxv = __fdiv_rn((float)w + 0.5f, 160.0f);
            float dx  = __fdiv_rn(__fsub_rn(g.x, rxv), g.z);
            s_dxx[slot * 160 + w] = __fmul_rn(dx, dx);
        } else {
            int py = w - 160;
            float ryv = __fdiv_rn((float)py + 0.5f, 160.0f);
            float dy  = __fdiv_rn(__fsub_rn(g.y, ryv), g.w);
            s_dyy[slot * 160 + py] = __fmul_rn(dy, dy);
        }
    }
    __syncthreads();
    int actcnt = s_actcnt;

    for (int j = 0; j < actcnt; j++) {
        // invariant at loop top: all prior claims visible (barrier B / fallback barrier)
        int slot = s_actlist[j];
        int4 m  = s_meta[slot];
        float4 g = s_geo[slot];
        const float* dxx = s_dxx + slot * 160;
        const float* dyy = s_dyy + slot * 160;

        // conservative rect: superset of {d < 0.5} (|dx_n| < sqrt(0.5) per axis), +slop
        float ex = __fmul_rn(g.z, 0.70711f);
        float ey = __fmul_rn(g.w, 0.70711f);
        int x0 = max(0,   (int)floorf((g.x - ex) * 160.0f - 0.5f) - 1);
        int x1 = min(159, (int)ceilf ((g.x + ex) * 160.0f - 0.5f) + 1);
        int y0 = max(0,   (int)floorf((g.y - ey) * 160.0f - 0.5f) - 1);
        int y1 = min(159, (int)ceilf ((g.y + ey) * 160.0f - 0.5f) + 1);
        int rw = x1 - x0 + 1;
        int M  = rw * (y1 - y0 + 1);

        // single scan with inline claiming: if inner.any() the ref claims exactly the
        // unclaimed inner points — each point is visited by exactly one thread, so a
        // claim can't change any other decision for this gt. If no thread claims,
        // state is unchanged and the fallback below is exact.
        unsigned base = PK_CLAIM | ((unsigned)m.x << PK_LAB_SH) |
                        ((unsigned)m.y << PK_ID_SH) | PK_MDV |
                        ((unsigned)m.x << PK_MDC_SH) |
                        ((unsigned)m.w << PK_MDN_SH);
        int found = 0;
        {
            // division-free strided (r,c) walk: one div per gt, then stepping
            int r  = tid / rw;                 // only vector div in the loop body
            int c  = tid - r * rw;
            int dr = TPB / rw;                 // uniform per gt
            int dc = TPB - dr * rw;            // TPB % rw
            for (int i = tid; i < M; i += TPB) {
                int px = x0 + c;
                int py = y0 + r;
                int p  = py * 160 + px;
                if (!(s_pack[p] & PK_CLAIM)) {
                    float d = __fadd_rn(dxx[px], dyy[py]);   // == point_dist exactly
                    if (d < INNER_TH) {        // score recomputed in scatter from (n,p)
                        s_pack[p] = base;
                        found = 1;
                    }
                }
                c += dc; r += dr;
                if (c >= rw) { c -= rw; r++; }
            }
        }
        if (found) s_any[j] = 1;
        __syncthreads();                       // B: consensus + claims visible

        if (!s_any[j]) {
            // fallback: single argmin over suppressed full frame (exact ref semantics:
            // claimed points hold 1e9; ties -> first index). No claims happened above.
            unsigned long long key = ~0ULL;
            {
                int py = tid / 160;            // one div
                int px = tid - py * 160;
                for (int p = tid; p < PP; p += TPB) {
                    float deff;
                    if (s_pack[p] & PK_CLAIM) {
                        deff = SUPP;
                    } else {
                        deff = __fadd_rn(dxx[px], dyy[py]);  // == point_dist exactly
                    }
                    unsigned long long kk =
                        ((unsigned long long)__float_as_uint(deff) << 32) |
                        (unsigned long long)(unsigned)p;
                    key = (kk < key) ? kk : key;
                    px += 64; py += 6;         // 1024 = 6*160 + 64
                    if (px >= 160) { px -= 160; py++; }
                }
            }
            unsigned long long v = key;
            for (int off = 32; off > 0; off >>= 1) {
                unsigned long long o = shfl_down_u64(v, off);
                v = (o < v) ? o : v;
            }
            int lane = tid & 63, wave = tid >> 6;
            if (lane == 0) s_wave[wave] = v;
            __syncthreads();
            if (tid == 0) {
                unsigned long long mval = s_wave[0];
                for (int w = 1; w < TPB / 64; w++) mval = (s_wave[w] < mval) ? s_wave[w] : mval;
                s_bcast = mval;
            }
            __syncthreads();
            unsigned long long gmin = s_bcast;
            float minv = __uint_as_float((unsigned)(gmin >> 32));
            int minp = (int)(unsigned)(gmin & 0xffffffffu);
            if ((minp & (TPB - 1)) == tid) {   // unique owner thread
                unsigned npk = PK_CLAIM | ((unsigned)m.x << PK_LAB_SH) |
                               ((unsigned)m.y << PK_ID_SH);
                if (minv < SUPP) {
                    // winner was unclaimed: d >= 0.5 everywhere unclaimed => ref md
                    // write = 0 on an all-zero row: no md record.
                    s_pack[minp] = npk;
                } else {
                    // all points claimed (argmin of all-1e9 = index 0). ref writes
                    // md[minp][lab] = 0: erase prior record iff same class.
                    unsigned old = s_pack[minp];
                    unsigned mdbits = old & (PK_MDV | (63u << PK_MDC_SH) | (31u << PK_MDN_SH));
                    if ((old & PK_MDV) &&
                        ((old >> PK_MDC_SH) & 63u) == (unsigned)m.x) mdbits = 0u;
                    s_pack[minp] = npk | mdbits;
                }
            }
            __syncthreads();                   // fallback claim visible before next gt
        }
        // common path: barrier B already made this gt's claims visible
    }

    // ---- dump pack state (coalesced; consumed by scatter_kernel) ----
    __syncthreads();
    uint4* dst = (uint4*)(packs_g + (size_t)bt * PP);
    for (int i = tid; i < PP / 4; i += TPB) dst[i] = ((const uint4*)s_pack)[i];
}

// ---------------- kernel 2: dense ml/mi write + sparse md scatter ----------------
// md zeros were already written by kernel 1's fill blocks; only points carrying an
// md record (PK_MDV) get their single nonzero class score written here. Score
// recompute uses the exact same IEEE ops as the match tables (make_geo + point_dist).
__global__ __launch_bounds__(256) void scatter_kernel(
        const unsigned* __restrict__ packs,
        const float*    __restrict__ gt_boxes,
        float* __restrict__ out) {
    const int    ML = BB * TT * PP;                  // 819200 floats
    const size_t MD = (size_t)BB * TT * PP * CC;     // 32768000 floats
    int f = blockIdx.x * 256 + threadIdx.x;          // uint4 index, [0, 204800)
    uint4 pk4 = ((const uint4*)packs)[f];

    float4 vml, vmi;
    vml.x = (pk4.x & PK_CLAIM) ? (float)((pk4.x >> PK_LAB_SH) & 63u) : -1.0f;
    vml.y = (pk4.y & PK_CLAIM) ? (float)((pk4.y >> PK_LAB_SH) & 63u) : -1.0f;
    vml.z = (pk4.z & PK_CLAIM) ? (float)((pk4.z >> PK_LAB_SH) & 63u) : -1.0f;
    vml.w = (pk4.w & PK_CLAIM) ? (float)((pk4.w >> PK_LAB_SH) & 63u) : -1.0f;
    vmi.x = (pk4.x & PK_CLAIM) ? (float)((pk4.x >> PK_ID_SH) & 127u) : -1.0f;
    vmi.y = (pk4.y & PK_CLAIM) ? (float)((pk4.y >> PK_ID_SH) & 127u) : -1.0f;
    vmi.z = (pk4.z & PK_CLAIM) ? (float)((pk4.z >> PK_ID_SH) & 127u) : -1.0f;
    vmi.w = (pk4.w & PK_CLAIM) ? (float)((pk4.w >> PK_ID_SH) & 127u) : -1.0f;
    ((float4*)out)[f] = vml;                         // ml
    ((float4*)(out + ML + MD))[f] = vmi;             // mi

    int pt0 = f << 2;
#pragma unroll
    for (int k = 0; k < 4; k++) {
        unsigned pk = (k == 0) ? pk4.x : (k == 1) ? pk4.y : (k == 2) ? pk4.z : pk4.w;
        if (pk & PK_MDV) {
            int pt  = pt0 + k;
            int cls = (int)((pk >> PK_MDC_SH) & 63u);
            int n   = (int)((pk >> PK_MDN_SH) & 31u);
            int bt  = pt / PP;
            int p   = pt - bt * PP;
            int py  = p / 160;
            int px  = p - py * 160;
            float4 g = make_geo(gt_boxes, bt >> 3, n, bt & 7);
            float d  = point_dist(px, py, g);
            out[ML + (size_t)pt * CC + cls] = __fsub_rn(1.0f, __fmul_rn(2.0f, d));
        }
    }
}

extern "C" void kernel_launch(void* const* d_in, const int* in_sizes, int n_in,
                              void* d_out, int out_size, void* d_ws, size_t ws_size,
                              hipStream_t stream) {
    const int*   gt_labels = (const int*)d_in[0];
    const float* gt_boxes  = (const float*)d_in[1];
    const int*   gt_ids    = (const int*)d_in[2];
    // d_in[3] = ref_points (regular 160x160 grid — computed exactly in-kernel)
    // d_in[4] = spatial_shapes (unused; H=W=160 fixed)

    unsigned* packs = (unsigned*)d_ws;            // 3.2 MB
    float*    outf  = (float*)d_out;

    // kernel 1: match on 32 blocks + md zero-fill on 224 blocks (overlapped)
    match_fill_kernel<<<BB * TT + FILLB, TPB, 0, stream>>>(
        gt_labels, gt_boxes, gt_ids, packs,
        (uint4*)(outf + BB * TT * PP));           // md region base (16B-aligned)

    // kernel 2: ml/mi dense + md sparse scatter
    scatter_kernel<<<(BB * TT * PP / 4) / 256, 256, 0, stream>>>(packs, gt_boxes, outf);
}

// Round 3
// 165.290 us; speedup vs baseline: 1.3570x; 1.0210x over previous
//
#include <hip/hip_runtime.h>

#define BB   4
#define NGT  20
#define TT   8
#define PP   25600
#define CC   40
#define TPB  1024
#define SUPP 1e9f
#define INNER_TH 0.5f
#define FILLB 224   // fill blocks in kernel 1: 32 match + 224 fill = 256 = one per CU

// pack bits: [0]=claimed [1:6]=ml label [7:13]=mi id [14]=md valid
//            [15:20]=md class [21:25]=md raw-gt-index (for exact score recompute)
#define PK_CLAIM  1u
#define PK_LAB_SH 1
#define PK_ID_SH  7
#define PK_MDV    (1u << 14)
#define PK_MDC_SH 15
#define PK_MDN_SH 21

__device__ inline unsigned long long shfl_down_u64(unsigned long long v, int off) {
    unsigned lo = (unsigned)v, hi = (unsigned)(v >> 32);
    lo = __shfl_down(lo, off, 64);
    hi = __shfl_down(hi, off, 64);
    return ((unsigned long long)hi << 32) | (unsigned long long)lo;
}

// geometry for (b, raw n, t) — identical IEEE ops in match and scatter
__device__ inline float4 make_geo(const float* __restrict__ gt_boxes, int b, int n, int t) {
    const float* bx = gt_boxes + ((size_t)(b * NGT + n) * TT + t) * 4;
    float x1 = bx[0], y1 = bx[1], x2 = bx[2], y2 = bx[3];
    float4 g;
    g.x = __fmul_rn(__fadd_rn(x1, x2), 0.5f);
    g.y = __fmul_rn(__fadd_rn(y1, y2), 0.5f);
    g.z = fmaxf(__fsub_rn(x2, x1), 0.05f);
    g.w = fmaxf(__fsub_rn(y2, y1), 0.05f);
    return g;
}

// exact distance for grid point (px,py) vs gt geometry g — identical IEEE ops to ref.
// d separates as dxx(px) + dyy(py); match precomputes axis tables with these exact
// ops and combines with the same final __fadd_rn → bit-identical (scatter uses this
// directly).
__device__ inline float point_dist(int px, int py, float4 g) {
    float rxv = __fdiv_rn((float)px + 0.5f, 160.0f);  // == ref_points formula exactly
    float ryv = __fdiv_rn((float)py + 0.5f, 160.0f);
    float dx = __fdiv_rn(__fsub_rn(g.x, rxv), g.z);
    float dy = __fdiv_rn(__fsub_rn(g.y, ryv), g.w);
    return __fadd_rn(__fmul_rn(dx, dx), __fmul_rn(dy, dy));  // no FMA contraction
}

// ---------------- kernel 1: blocks [0,32) = match; blocks [32,256) = md zero-fill --
__global__ __launch_bounds__(TPB) void match_fill_kernel(
        const int*   __restrict__ gt_labels,
        const float* __restrict__ gt_boxes,
        const int*   __restrict__ gt_ids,
        unsigned* __restrict__ packs_g,   // [B*T][P]
        uint4*    __restrict__ md4) {     // md region of d_out, as uint4
    if (blockIdx.x >= BB * TT) {
        const int MD4 = BB * TT * PP * CC / 4;      // 8,192,000 uint4
        const int stride = FILLB * TPB;             // 229,376
        uint4 z = make_uint4(0u, 0u, 0u, 0u);
        for (int i = (blockIdx.x - BB * TT) * TPB + (int)threadIdx.x; i < MD4; i += stride)
            md4[i] = z;
        return;
    }

    int bt = blockIdx.x;            // b*T + t
    int b  = bt >> 3;
    int t  = bt & 7;
    int tid = threadIdx.x;

    __shared__ unsigned s_pack[PP];           // 102400 B
    __shared__ unsigned s_mask[160 * 5];      // 3200 B: claimed bitmask, 160b per row
    __shared__ float  s_dxx[NGT * 160];       // 12800 B: per-slot column dx^2
    __shared__ float  s_dyy[NGT * 160];       // 12800 B: per-slot row dy^2
    __shared__ float  s_area[NGT];
    __shared__ int    s_valid[NGT];
    __shared__ int    s_order[NGT];
    __shared__ int    s_any[NGT];             // one flag per active slot: never reused
    __shared__ float4 s_geo[NGT];
    __shared__ int4   s_meta[NGT];            // {label, id, active, raw n} (sorted order)
    __shared__ int    s_actlist[NGT];
    __shared__ int    s_actcnt;
    __shared__ unsigned long long s_wave[TPB / 64];
    __shared__ unsigned long long s_bcast;

    // ---- phase 0: zero pack state + claim mask, per-gt mean area / validity ----
    {
        uint4 z = make_uint4(0u, 0u, 0u, 0u);
        for (int i = tid; i < PP / 4; i += TPB) ((uint4*)s_pack)[i] = z;
    }
    if (tid < 160 * 5) s_mask[tid] = 0u;
    if (tid < NGT) {
        const float* bx = gt_boxes + (size_t)(b * NGT + tid) * TT * 4;
        float a[TT];
        int anyPos = 0;
        for (int f = 0; f < TT; f++) {
            float w = __fsub_rn(bx[f * 4 + 2], bx[f * 4 + 0]);
            float h = __fsub_rn(bx[f * 4 + 3], bx[f * 4 + 1]);
            a[f] = __fmul_rn(w, h);
            anyPos |= (w > 0.0f && h > 0.0f) ? 1 : 0;
        }
        // numpy pairwise sum order for n=8, then * 1/8
        float s = __fadd_rn(__fadd_rn(__fadd_rn(a[0], a[1]), __fadd_rn(a[2], a[3])),
                            __fadd_rn(__fadd_rn(a[4], a[5]), __fadd_rn(a[6], a[7])));
        s_area[tid]  = __fmul_rn(s, 0.125f);
        s_valid[tid] = (anyPos && gt_labels[b * NGT + tid] >= 0) ? 1 : 0;
        s_any[tid]   = 0;
    }
    __syncthreads();

    // ---- phase 1: stable ascending argsort by rank counting ----
    if (tid < NGT) {
        float an = s_area[tid];
        int r = 0;
        for (int m2 = 0; m2 < NGT; m2++) {
            float am = s_area[m2];
            r += (am < an || (am == an && m2 < tid)) ? 1 : 0;
        }
        s_order[r] = tid;
    }
    __syncthreads();

    // ---- phase 2: per sorted slot, this frame's geometry/meta; compact active list --
    if (tid < NGT) {
        int n   = s_order[tid];
        int src = b * NGT + n;
        s_geo[tid] = make_geo(gt_boxes, b, n, t);
        int id = gt_ids[src * TT + t];
        int4 mm;
        mm.x = gt_labels[src];
        mm.y = id;
        mm.z = (s_valid[n] && id != -1) ? 1 : 0;
        mm.w = n;                              // raw index for scatter's score recompute
        s_meta[tid] = mm;
    }
    __syncthreads();
    if (tid == 0) {
        int c = 0;
        for (int k = 0; k < NGT; k++)
            if (s_meta[k].z) s_actlist[c++] = k;  // preserves sorted order
        s_actcnt = c;
    }

    // ---- phase 2.5: separable distance tables, all slots at once ----
    // dxx[slot][px] = sq((cx - rx(px))/w), dyy[slot][py] = sq((cy - ry(py))/h),
    // exact IEEE ops of point_dist; replaces 2 divisions per scanned point below.
    for (int i = tid; i < NGT * 320; i += TPB) {
        int slot = i / 320;                   // magic-mul, constant divisor
        int w    = i - slot * 320;
        float4 g = s_geo[slot];               // written before the last barrier
        if (w < 160) {
            float rxv = __fdiv_rn((float)w + 0.5f, 160.0f);
            float dx  = __fdiv_rn(__fsub_rn(g.x, rxv), g.z);
            s_dxx[slot * 160 + w] = __fmul_rn(dx, dx);
        } else {
            int py = w - 160;
            float ryv = __fdiv_rn((float)py + 0.5f, 160.0f);
            float dy  = __fdiv_rn(__fsub_rn(g.y, ryv), g.w);
            s_dyy[slot * 160 + py] = __fmul_rn(dy, dy);
        }
    }
    __syncthreads();
    int actcnt = s_actcnt;

    for (int j = 0; j < actcnt; j++) {
        // invariant at loop top: all prior claims visible (barrier B / fallback barrier)
        int slot = s_actlist[j];
        int4 m  = s_meta[slot];
        float4 g = s_geo[slot];
        const float* dxx = s_dxx + slot * 160;
        const float* dyy = s_dyy + slot * 160;

        // conservative rect: superset of {d < 0.5} (|dx_n| < sqrt(0.5) per axis), +slop
        float ex = __fmul_rn(g.z, 0.70711f);
        float ey = __fmul_rn(g.w, 0.70711f);
        int x0 = max(0,   (int)floorf((g.x - ex) * 160.0f - 0.5f) - 1);
        int x1 = min(159, (int)ceilf ((g.x + ex) * 160.0f - 0.5f) + 1);
        int y0 = max(0,   (int)floorf((g.y - ey) * 160.0f - 0.5f) - 1);
        int y1 = min(159, (int)ceilf ((g.y + ey) * 160.0f - 0.5f) + 1);
        int rw = x1 - x0 + 1;
        int M  = rw * (y1 - y0 + 1);

        // single scan with inline claiming (exact: each point visited by one thread;
        // a claim can't change any other decision for this gt). If nothing claimed,
        // state is unchanged and the fallback below is exact.
        unsigned base = PK_CLAIM | ((unsigned)m.x << PK_LAB_SH) |
                        ((unsigned)m.y << PK_ID_SH) | PK_MDV |
                        ((unsigned)m.x << PK_MDC_SH) |
                        ((unsigned)m.w << PK_MDN_SH);
        int found = 0;
        {
            // division-free strided (r,c) walk: one div per gt, then stepping
            int r  = tid / rw;                 // only vector div in the loop body
            int c  = tid - r * rw;
            int dr = TPB / rw;                 // uniform per gt
            int dc = TPB - dr * rw;            // TPB % rw
            for (int i = tid; i < M; i += TPB) {
                int px = x0 + c;
                int py = y0 + r;
                int p  = py * 160 + px;
                if (!(s_pack[p] & PK_CLAIM)) {
                    float d = __fadd_rn(dxx[px], dyy[py]);   // == point_dist exactly
                    if (d < INNER_TH) {        // score recomputed in scatter from (n,p)
                        s_pack[p] = base;
                        atomicOr(&s_mask[p >> 5], 1u << (p & 31));  // claim bit
                        found = 1;
                    }
                }
                c += dc; r += dr;
                if (c >= rw) { c -= rw; r++; }
            }
        }
        if (found) s_any[j] = 1;
        __syncthreads();                       // B: consensus + claims visible

        if (!s_any[j]) {
            // fallback argmin over unclaimed, O(rows): dxx is weakly unimodal in x
            // (exact monotone ops + monotone rounding), so per row the min over
            // unclaimed x is at the nearest unclaimed x each side of the vertex.
            // Mid candidates xs,xs+1 absorb ±1 float slack in the vertex index;
            // left-side plateau walk preserves exact tie -> smallest p. All d values
            // use the same table entries + final __fadd_rn as the full scan did.
            unsigned long long key = ~0ULL;
            if (tid < 160) {
                int y = tid;
                unsigned um[5];
#pragma unroll
                for (int w = 0; w < 5; w++) um[w] = ~s_mask[y * 5 + w];
                unsigned anyu = um[0] | um[1] | um[2] | um[3] | um[4];
                if (!anyu) {
                    // empty row: row 0 supplies the all-claimed sentinel (SUPP, p=0);
                    // SUPP only wins the global min when every row is empty (real
                    // d <= ~650 << 1e9), matching ref argmin of all-1e9 -> index 0.
                    if (y == 0)
                        key = ((unsigned long long)__float_as_uint(SUPP) << 32);
                } else {
                    float dyyv = dyy[y];
                    int xs = (int)floorf(__fsub_rn(__fmul_rn(g.x, 160.0f), 0.5f));
                    xs = min(max(xs, -2), 161);
                    float bd = 2e9f;           // > any real d; never ties real d
                    int   bx = -1;
                    // explicit mid candidates xs, xs+1
#pragma unroll
                    for (int k2 = 0; k2 < 2; k2++) {
                        int x = xs + k2;
                        if (x >= 0 && x <= 159 && ((um[x >> 5] >> (x & 31)) & 1u)) {
                            float d2 = __fadd_rn(dxx[x], dyyv);
                            if (d2 < bd || (d2 == bd && x < bx)) { bd = d2; bx = x; }
                        }
                    }
                    // left region x <= xs-1: weakly decreasing toward xs -> nearest
                    // unclaimed is the min; plateau-walk left for tie -> smallest x
                    {
                        int xq = min(xs - 1, 159);
                        int xL = -1;
                        if (xq >= 0) {
                            int w = xq >> 5;
                            unsigned mm = um[w] & (0xffffffffu >> (31 - (xq & 31)));
                            while (true) {
                                if (mm) { xL = (w << 5) + (31 - __clz(mm)); break; }
                                if (--w < 0) break;
                                mm = um[w];
                            }
                        }
                        if (xL >= 0) {
                            float dL = __fadd_rn(dxx[xL], dyyv);
                            while (xL > 0) {   // exact-equality plateau walk
                                int xq2 = xL - 1;
                                int w = xq2 >> 5;
                                unsigned mm = um[w] & (0xffffffffu >> (31 - (xq2 & 31)));
                                int x2 = -1;
                                while (true) {
                                    if (mm) { x2 = (w << 5) + (31 - __clz(mm)); break; }
                                    if (--w < 0) break;
                                    mm = um[w];
                                }
                                if (x2 < 0) break;
                                if (__fadd_rn(dxx[x2], dyyv) != dL) break;
                                xL = x2;
                            }
                            if (dL < bd || (dL == bd && xL < bx)) { bd = dL; bx = xL; }
                        }
                    }
                    // right region x >= xs+2: weakly increasing -> nearest unclaimed
                    // is min AND smallest x of any plateau (no walk needed)
                    {
                        int xq = max(xs + 2, 0);
                        int xR = -1;
                        if (xq <= 159) {
                            int w = xq >> 5;
                            unsigned mm = um[w] & (0xffffffffu << (xq & 31));
                            while (true) {
                                if (mm) { xR = (w << 5) + (__ffs(mm) - 1); break; }
                                if (++w > 4) break;
                                mm = um[w];
                            }
                        }
                        if (xR >= 0) {
                            float dR = __fadd_rn(dxx[xR], dyyv);
                            if (dR < bd || (dR == bd && xR < bx)) { bd = dR; bx = xR; }
                        }
                    }
                    if (bx >= 0) {
                        int p = y * 160 + bx;
                        key = ((unsigned long long)__float_as_uint(bd) << 32) |
                              (unsigned long long)(unsigned)p;
                    }
                }
            }
            // global (d, p) min over the 160 row keys (others hold ~0ULL)
            unsigned long long v = key;
            for (int off = 32; off > 0; off >>= 1) {
                unsigned long long o = shfl_down_u64(v, off);
                v = (o < v) ? o : v;
            }
            int lane = tid & 63, wave = tid >> 6;
            if (lane == 0) s_wave[wave] = v;
            __syncthreads();
            if (tid == 0) {
                unsigned long long mval = s_wave[0];
                for (int w = 1; w < TPB / 64; w++) mval = (s_wave[w] < mval) ? s_wave[w] : mval;
                s_bcast = mval;
            }
            __syncthreads();
            unsigned long long gmin = s_bcast;
            float minv = __uint_as_float((unsigned)(gmin >> 32));
            int minp = (int)(unsigned)(gmin & 0xffffffffu);
            if ((minp & (TPB - 1)) == tid) {   // unique owner thread
                unsigned npk = PK_CLAIM | ((unsigned)m.x << PK_LAB_SH) |
                               ((unsigned)m.y << PK_ID_SH);
                if (minv < SUPP) {
                    // winner was unclaimed: d >= 0.5 everywhere unclaimed => ref md
                    // write = 0 on an all-zero row: no md record.
                    s_pack[minp] = npk;
                } else {
                    // all points claimed (argmin of all-1e9 = index 0). ref writes
                    // md[minp][lab] = 0: erase prior record iff same class.
                    unsigned old = s_pack[minp];
                    unsigned mdbits = old & (PK_MDV | (63u << PK_MDC_SH) | (31u << PK_MDN_SH));
                    if ((old & PK_MDV) &&
                        ((old >> PK_MDC_SH) & 63u) == (unsigned)m.x) mdbits = 0u;
                    s_pack[minp] = npk | mdbits;
                }
                atomicOr(&s_mask[minp >> 5], 1u << (minp & 31));  // keep mask in sync
            }
            __syncthreads();                   // fallback claim visible before next gt
        }
        // common path: barrier B already made this gt's claims visible
    }

    // ---- dump pack state (coalesced; consumed by scatter_kernel) ----
    __syncthreads();
    uint4* dst = (uint4*)(packs_g + (size_t)bt * PP);
    for (int i = tid; i < PP / 4; i += TPB) dst[i] = ((const uint4*)s_pack)[i];
}

// ---------------- kernel 2: dense ml/mi write + sparse md scatter ----------------
// md zeros already written by kernel 1's fill blocks; only points carrying an md
// record get their single nonzero class score written (exact IEEE recompute).
__global__ __launch_bounds__(256) void scatter_kernel(
        const unsigned* __restrict__ packs,
        const float*    __restrict__ gt_boxes,
        float* __restrict__ out) {
    const int    ML = BB * TT * PP;                  // 819200 floats
    const size_t MD = (size_t)BB * TT * PP * CC;     // 32768000 floats
    int f = blockIdx.x * 256 + threadIdx.x;          // uint4 index, [0, 204800)
    uint4 pk4 = ((const uint4*)packs)[f];

    float4 vml, vmi;
    vml.x = (pk4.x & PK_CLAIM) ? (float)((pk4.x >> PK_LAB_SH) & 63u) : -1.0f;
    vml.y = (pk4.y & PK_CLAIM) ? (float)((pk4.y >> PK_LAB_SH) & 63u) : -1.0f;
    vml.z = (pk4.z & PK_CLAIM) ? (float)((pk4.z >> PK_LAB_SH) & 63u) : -1.0f;
    vml.w = (pk4.w & PK_CLAIM) ? (float)((pk4.w >> PK_LAB_SH) & 63u) : -1.0f;
    vmi.x = (pk4.x & PK_CLAIM) ? (float)((pk4.x >> PK_ID_SH) & 127u) : -1.0f;
    vmi.y = (pk4.y & PK_CLAIM) ? (float)((pk4.y >> PK_ID_SH) & 127u) : -1.0f;
    vmi.z = (pk4.z & PK_CLAIM) ? (float)((pk4.z >> PK_ID_SH) & 127u) : -1.0f;
    vmi.w = (pk4.w & PK_CLAIM) ? (float)((pk4.w >> PK_ID_SH) & 127u) : -1.0f;
    ((float4*)out)[f] = vml;                         // ml
    ((float4*)(out + ML + MD))[f] = vmi;             // mi

    int pt0 = f << 2;
#pragma unroll
    for (int k = 0; k < 4; k++) {
        unsigned pk = (k == 0) ? pk4.x : (k == 1) ? pk4.y : (k == 2) ? pk4.z : pk4.w;
        if (pk & PK_MDV) {
            int pt  = pt0 + k;
            int cls = (int)((pk >> PK_MDC_SH) & 63u);
            int n   = (int)((pk >> PK_MDN_SH) & 31u);
            int bt  = pt / PP;
            int p   = pt - bt * PP;
            int py  = p / 160;
            int px  = p - py * 160;
            float4 g = make_geo(gt_boxes, bt >> 3, n, bt & 7);
            float d  = point_dist(px, py, g);
            out[ML + (size_t)pt * CC + cls] = __fsub_rn(1.0f, __fmul_rn(2.0f, d));
        }
    }
}

extern "C" void kernel_launch(void* const* d_in, const int* in_sizes, int n_in,
                              void* d_out, int out_size, void* d_ws, size_t ws_size,
                              hipStream_t stream) {
    const int*   gt_labels = (const int*)d_in[0];
    const float* gt_boxes  = (const float*)d_in[1];
    const int*   gt_ids    = (const int*)d_in[2];
    // d_in[3] = ref_points (regular 160x160 grid — computed exactly in-kernel)
    // d_in[4] = spatial_shapes (unused; H=W=160 fixed)

    unsigned* packs = (unsigned*)d_ws;            // 3.2 MB
    float*    outf  = (float*)d_out;

    // kernel 1: match on 32 blocks + md zero-fill on 224 blocks (overlapped)
    match_fill_kernel<<<BB * TT + FILLB, TPB, 0, stream>>>(
        gt_labels, gt_boxes, gt_ids, packs,
        (uint4*)(outf + BB * TT * PP));           // md region base (16B-aligned)

    // kernel 2: ml/mi dense + md sparse scatter
    scatter_kernel<<<(BB * TT * PP / 4) / 256, 256, 0, stream>>>(packs, gt_boxes, outf);
}